// Round 12
// baseline (227.305 us; speedup 1.0000x reference)
//
#include <hip/hip_runtime.h>
#include <hip/hip_bf16.h>
#include <hip/hip_fp16.h>

// INPUTS/OUTPUT ARE FLOAT32 (R1/R3/R4 NaN'd reading them as bf16).
// PERF NOTES:
//  - R5: bounds(256,4) forced VGPR 64 -> ~50 scratch spills, FETCH 514 MB,
//    2.6x slower. Keep (256,2); never force a budget below natural usage.
//  - Cost model R6..R11: occupancy tracks total regs (64->43%, ~100->20%);
//    at ~20% occ, eff. cyc/instr ~3.3 (latency bubbles). Trans floor 27 us,
//    VALU floor 26 us -> occupancy is the dominant lever now.
//  - R12: w1 + W2-frags moved to LDS (re-read per m-step, conflict-free
//    layouts); asm memory clobber per iteration stops LICM re-hoisting them
//    into registers. Target: cross a wave-residency boundary.

#define NTOT 2048
#define MTOT 2048
#define MSPLIT 32
#define MCHUNK 64   // == per-block m range: single staging chunk

typedef _Float16 f16x8  __attribute__((ext_vector_type(8)));
typedef _Float16 f16x16 __attribute__((ext_vector_type(16)));
typedef float f32x4  __attribute__((ext_vector_type(4)));
typedef float f32x2  __attribute__((ext_vector_type(2)));

// exp(x) = 2^(x*log2e); sigmoid(x) = 1/(1+2^(-x*log2e))
#define NL2E (-1.4426950408889634f)
// exp(-d2/5) = 2^(d2 * -log2e/5)
#define C1E  (-0.2885390081777927f)

__device__ __forceinline__ float fast_exp2(float x) {
#if __has_builtin(__builtin_amdgcn_exp2f)
  return __builtin_amdgcn_exp2f(x);
#else
  return __exp2f(x);
#endif
}
__device__ __forceinline__ float fast_rcp(float x) {
#if __has_builtin(__builtin_amdgcn_rcpf)
  return __builtin_amdgcn_rcpf(x);
#else
  return 1.0f / x;
#endif
}
__device__ __forceinline__ float fast_rsq(float x) {
#if __has_builtin(__builtin_amdgcn_rsqf)
  return __builtin_amdgcn_rsqf(x);
#else
  return rsqrtf(x);
#endif
}
__device__ __forceinline__ f32x2 pk_fma(f32x2 a, f32x2 b, f32x2 c) {
  return __builtin_elementwise_fma(a, b, c);
}
__device__ __forceinline__ f16x16 pk_fma16(f16x16 a, f16x16 b, f16x16 c) {
  return __builtin_elementwise_fma(a, b, c);
}

union F16U { f16x16 v; __half2 h[8]; f16x8 a[2]; };

// ---------------------------------------------------------------------------
// Edge phase: per wave, 16 n-rows; loop over this block's 64-m range.
// layer1+silu packed f16 (weights re-read from LDS each step) -> f16 A-frags
// -> mfma_16x16x32_f16 (W2 B-frags re-read from LDS) -> sigmoid f32 ->
// num/den f32 regs -> atomicAdd. Grid: (NTOT/64)*MSPLIT = 1024 blocks of 256.
// ---------------------------------------------------------------------------
__global__ __launch_bounds__(256, 2)
void edge_kernel(const float* __restrict__ h_l,
                 const float* __restrict__ x_l,
                 const float* __restrict__ h_r,
                 const float* __restrict__ x_r,
                 const float* __restrict__ W1,
                 const float* __restrict__ b1,
                 const float* __restrict__ W2,
                 const float* __restrict__ b2,
                 float* __restrict__ num_g,
                 float* __restrict__ den_g) {
  // hrT[ms][l15*4 + c] = h_r[m][c*16 + l15]  (per-lane float4 -> ds_read_b128)
  __shared__ float hrT[MCHUNK][64];                 // 16 KB
  __shared__ float xr_s[MCHUNK][8];                 // 2 KB
  // W2 frags: w2L[(((c*2+h)*4+quad)*16+l15)*8 + j] = (f16)W2[(h*32+quad*8+j)*64 + c*16+l15]
  __shared__ __align__(16) _Float16 w2L[4096];      // 8 KB
  // w1: per-quad block of 72 halves (144 B => quad banks {0,4,8,12}, conflict-free):
  //   [arr(4: d,h,y,b) * 16 halves][j = pp*2+hilo], pad 8 halves
  __shared__ __align__(16) _Float16 w1L[4 * 72];    // 576 B

  const int tid  = threadIdx.x;
  const int wave = tid >> 6;
  const int lane = tid & 63;
  const int l15  = lane & 15;
  const int quad = lane >> 4;

  const int nblk   = blockIdx.x / MSPLIT;
  const int msplit = blockIdx.x % MSPLIT;
  const int n0     = nblk * 64 + wave * 16;
  const int mBase  = msplit * MCHUNK;

  // per-lane A-row n
  const int nA = n0 + l15;
  const float xl0 = x_l[nA * 3 + 0];
  const float xl1 = x_l[nA * 3 + 1];
  const float xl2 = x_l[nA * 3 + 2];
  const float lp0 = h_l[nA * 64 + 61];
  const float lp1 = h_l[nA * 64 + 62];
  const float lp2 = h_l[nA * 64 + 63];

  // stage W2 frags into LDS
  for (int idx = tid; idx < 4096; idx += 256) {
    const int j = idx & 7, i15 = (idx >> 3) & 15;
    const int q = (idx >> 7) & 3, hh = (idx >> 9) & 1, c = (idx >> 10) & 3;
    const int k = hh * 32 + q * 8 + j;
    w2L[idx] = (_Float16)W2[k * 64 + c * 16 + i15];
  }
  // stage w1 (b1 + W1 row 3 folded; edge_raw[3] == 1)
  {
    const int idx = tid;
    if (idx < 256) {
      const int q = idx >> 6, r = idx & 63;
      const int arr = r >> 4, pp = (r >> 1) & 7, hilo = r & 1;
      const int j = 2 * pp + hilo;
      const int hcol = (j < 8) ? (q * 8 + j) : (32 + q * 8 + (j - 8));
      float v;
      if (arr == 0)      v = W1[hcol];
      else if (arr == 1) v = W1[64 + hcol];
      else if (arr == 2) v = W1[128 + hcol];
      else               v = b1[hcol] + W1[192 + hcol];
      w1L[q * 72 + arr * 16 + pp * 2 + hilo] = (_Float16)v;
    }
  }
  // stage h_r chunk (transposed groups of 4) + x_r/r_p chunk
  for (int idx = tid; idx < MCHUNK * 64; idx += 256) {
    const int mm = idx >> 6, w = idx & 63;
    const int i = w >> 2, c = w & 3;
    hrT[mm][w] = h_r[(mBase + mm) * 64 + c * 16 + i];
  }
  for (int idx = tid; idx < MCHUNK * 8; idx += 256) {
    const int mm = idx >> 3, k = idx & 7;
    float v = 0.f;
    const int m = mBase + mm;
    if (k < 3)      v = x_r[m * 3 + k];
    else if (k < 6) v = h_r[m * 64 + 61 + (k - 3)];
    xr_s[mm][k] = v;
  }

  // b2 folded into sigmoid exp-arg: arg = e*NL2E + NL2E*b2[h2]
  f32x2 b2c2[4];
#pragma unroll
  for (int c = 0; c < 4; ++c) {
    const float v = NL2E * b2[c * 16 + l15];
    b2c2[c] = f32x2{v, v};
  }

  const f32x4 zero4 = {0.f, 0.f, 0.f, 0.f};
  const f32x2 one2 = {1.f, 1.f};
  const f32x2 nl2e2 = {NL2E, NL2E};
  const __half2 nl2eh = __float2half2_rn(NL2E);
  const __half2 oneh  = __float2half2_rn(1.0f);
  f32x2 numr2[4][2], denr2[4][2];
#pragma unroll
  for (int c = 0; c < 4; ++c)
#pragma unroll
    for (int h = 0; h < 2; ++h) {
      numr2[c][h] = f32x2{0.f, 0.f};
      denr2[c][h] = f32x2{0.f, 0.f};
    }

  __syncthreads();

  // per-lane LDS bases (loop-invariant addresses; loads stay in-loop)
  const f16x16* w1q = (const f16x16*)(w1L + quad * 72);        // [arr]
  const f16x8*  w2p = (const f16x8*)w2L + (quad * 16 + l15);   // [(c*2+h)*64]

#pragma unroll 1
  for (int ms = 0; ms < MCHUNK; ++ms) {
    asm volatile("" ::: "memory");  // keep LDS weight reads in-loop (anti-LICM)

    // broadcast per-m values
    const f32x4 xa = *(const f32x4*)&xr_s[ms][0];   // xr0 xr1 xr2 rp0
    const f32x2 xb = *(const f32x2*)&xr_s[ms][4];   // rp1 rp2
    const float dx = xl0 - xa[0], dy = xl1 - xa[1], dz = xl2 - xa[2];
    const float d2 = fmaf(dz, dz, fmaf(dy, dy, dx * dx));
    const float dist = fast_exp2(d2 * C1E);          // exp(-d2/5)
    const float hb = fmaf(lp1, xa[3], lp0 * xb[0]);
    const float hy = lp2 * xb[1];
    const __half2 dist2 = __float2half2_rn(dist);
    const __half2 hb2 = __float2half2_rn(hb);
    const __half2 hy2 = __float2half2_rn(hy);
    F16U distv, hbv, hyv;
#pragma unroll
    for (int p = 0; p < 8; ++p) { distv.h[p] = dist2; hbv.h[p] = hb2; hyv.h[p] = hy2; }

    // layer 1: t = dist*wd + hb*wh + hy*wy + b (packed f16; weights from LDS)
    const f16x16 wd = w1q[0];
    const f16x16 wh = w1q[1];
    const f16x16 wy = w1q[2];
    const f16x16 wb = w1q[3];
    F16U T;
    T.v = pk_fma16(distv.v, wd, pk_fma16(hbv.v, wh, pk_fma16(hyv.v, wy, wb)));

    // silu = t / (1 + 2^(t*NL2E)); f16 overflow tail -> s = 0 == silu tail.
    F16U S;
#pragma unroll
    for (int p = 0; p < 8; ++p) {
      const __half2 a2 = __hmul2(T.h[p], nl2eh);
      const __half2 e2 = h2exp2(a2);
      const __half2 dd = __hadd2(e2, oneh);
      const __half2 r2 = h2rcp(dd);
      S.h[p] = __hmul2(T.h[p], r2);
    }
    const f16x8 A0 = S.a[0];
    const f16x8 A1 = S.a[1];

    f32x4 acc[4];
#pragma unroll
    for (int c = 0; c < 4; ++c) {
      acc[c] = __builtin_amdgcn_mfma_f32_16x16x32_f16(A0, w2p[(c * 2 + 0) * 64], zero4, 0, 0, 0);
      acc[c] = __builtin_amdgcn_mfma_f32_16x16x32_f16(A1, w2p[(c * 2 + 1) * 64], acc[c], 0, 0, 0);
    }

    // sigmoid + accumulate (f32, r-pairs packed).
    // lane holds e[n = n0+quad*4+r][h2 = c*16+l15]; hrv per c via one b128.
    const f32x4 hrv4 = *(const f32x4*)&hrT[ms][l15 * 4];
#pragma unroll
    for (int c = 0; c < 4; ++c) {
      const f32x2 hrv2 = {hrv4[c], hrv4[c]};
#pragma unroll
      for (int h = 0; h < 2; ++h) {
        const f32x2 a2 = {acc[c][2 * h], acc[c][2 * h + 1]};
        const f32x2 arg = pk_fma(a2, nl2e2, b2c2[c]);
        f32x2 e2;
        e2.x = fast_exp2(arg.x);
        e2.y = fast_exp2(arg.y);
        const f32x2 dden = e2 + one2;
        f32x2 w2;
        w2.x = fast_rcp(dden.x);
        w2.y = fast_rcp(dden.y);
        numr2[c][h] = pk_fma(w2, hrv2, numr2[c][h]);
        denr2[c][h] = denr2[c][h] + w2;
      }
    }
  }

#pragma unroll
  for (int c = 0; c < 4; ++c)
#pragma unroll
    for (int h = 0; h < 2; ++h)
#pragma unroll
      for (int k = 0; k < 2; ++k) {
        const int r = 2 * h + k;
        const int n = n0 + quad * 4 + r;
        const int h2 = c * 16 + l15;
        atomicAdd(&num_g[n * 64 + h2], k ? numr2[c][h].y : numr2[c][h].x);
        atomicAdd(&den_g[n * 64 + h2], k ? denr2[c][h].y : denr2[c][h].x);
      }
}

// ---------------------------------------------------------------------------
// Node phase: one wave per row. h_agg = num/(den+1e-6); z = cat(h_l,h_agg)@Wn1
// + bn1 -> LN -> silu -> @Wn2 + bn2; out = h_l + z.
// ---------------------------------------------------------------------------
__global__ __launch_bounds__(256)
void node_kernel(const float* __restrict__ h_l,
                 const float* __restrict__ num_g,
                 const float* __restrict__ den_g,
                 const float* __restrict__ Wn1,
                 const float* __restrict__ bn1,
                 const float* __restrict__ ln_g,
                 const float* __restrict__ ln_b,
                 const float* __restrict__ Wn2,
                 const float* __restrict__ bn2,
                 float* __restrict__ out) {
  __shared__ float Wn1_s[128 * 64];
  __shared__ float Wn2_s[64 * 64];
  __shared__ float xbuf[4][128];
  __shared__ float zbuf[4][64];

  const int tid = threadIdx.x;
  for (int i = tid; i < 128 * 64; i += 256) Wn1_s[i] = Wn1[i];
  for (int i = tid; i < 64 * 64; i += 256) Wn2_s[i] = Wn2[i];

  const int wave = tid >> 6, lane = tid & 63;
  const int row = blockIdx.x * 4 + wave;

  const float hl = h_l[row * 64 + lane];
  const float dn = den_g[row * 64 + lane] + 1e-6f;
  const float hagg = num_g[row * 64 + lane] * fast_rcp(dn);
  xbuf[wave][lane] = hl;
  xbuf[wave][64 + lane] = hagg;
  __syncthreads();

  float t = bn1[lane];
#pragma unroll 8
  for (int k = 0; k < 128; ++k) t = fmaf(xbuf[wave][k], Wn1_s[k * 64 + lane], t);

  float s1 = t, s2 = t * t;
#pragma unroll
  for (int off = 32; off; off >>= 1) {
    s1 += __shfl_xor(s1, off);
    s2 += __shfl_xor(s2, off);
  }
  const float mu = s1 * 0.015625f;
  const float var = fmaf(s2, 0.015625f, -mu * mu);
  const float rs = fast_rsq(var + 1e-5f);
  const float zn = fmaf((t - mu) * rs, ln_g[lane], ln_b[lane]);
  const float sz = zn * fast_rcp(1.0f + fast_exp2(zn * NL2E));  // silu
  zbuf[wave][lane] = sz;
  __syncthreads();

  float o = bn2[lane];
#pragma unroll 8
  for (int k = 0; k < 64; ++k) o = fmaf(zbuf[wave][k], Wn2_s[k * 64 + lane], o);

  out[row * 64 + lane] = hl + o;
}

extern "C" void kernel_launch(void* const* d_in, const int* in_sizes, int n_in,
                              void* d_out, int out_size, void* d_ws, size_t ws_size,
                              hipStream_t stream) {
  const float* h_l = (const float*)d_in[0];
  const float* x_l = (const float*)d_in[1];
  const float* h_r = (const float*)d_in[2];
  const float* x_r = (const float*)d_in[3];
  const float* W1  = (const float*)d_in[4];
  const float* b1  = (const float*)d_in[5];
  const float* W2  = (const float*)d_in[6];
  const float* b2  = (const float*)d_in[7];
  const float* Wn1 = (const float*)d_in[8];
  const float* bn1 = (const float*)d_in[9];
  const float* lng = (const float*)d_in[10];
  const float* lnb = (const float*)d_in[11];
  const float* Wn2 = (const float*)d_in[12];
  const float* bn2 = (const float*)d_in[13];

  float* num_g = (float*)d_ws;
  float* den_g = num_g + (size_t)NTOT * 64;

  hipMemsetAsync(d_ws, 0, (size_t)NTOT * 64 * 2 * sizeof(float), stream);
  edge_kernel<<<dim3((NTOT / 64) * MSPLIT), dim3(256), 0, stream>>>(
      h_l, x_l, h_r, x_r, W1, b1, W2, b2, num_g, den_g);
  node_kernel<<<dim3(NTOT / 4), dim3(256), 0, stream>>>(
      h_l, num_g, den_g, Wn1, bn1, lng, lnb, Wn2, bn2, (float*)d_out);
}

// Round 13
// 219.956 us; speedup vs baseline: 1.0334x; 1.0334x over previous
//
#include <hip/hip_runtime.h>
#include <hip/hip_bf16.h>
#include <hip/hip_fp16.h>

// INPUTS/OUTPUT ARE FLOAT32 (R1/R3/R4 NaN'd reading them as bf16).
// PERF NOTES:
//  - R5: bounds(256,4) forced VGPR 64 -> scratch spills, FETCH 514 MB, 2.6x
//    slower. Keep (256,2); never force a budget below natural usage.
//  - R12: weights->LDS raised occupancy 20->32% but ds_read latency on the
//    critical path cost more than the bubbles saved (145.7->159 us).
//    Weights stay in REGISTERS. Edge below = exact R11 (best: 145.7 us).
//  - Gap (total - edge) ~= 70 us constant across rounds = node_kernel
//    staging 48 KB of weights per block for only 4 rows. R13: 8 rows/block,
//    wave-local row loop, no inner barriers.

#define NTOT 2048
#define MTOT 2048
#define MSPLIT 32
#define MCHUNK 64   // == per-block m range: single staging chunk
#define NODE_ROWS 8 // rows per node block (2 per wave)

typedef _Float16 f16x8 __attribute__((ext_vector_type(8)));
typedef float f32x4  __attribute__((ext_vector_type(4)));
typedef float f32x2  __attribute__((ext_vector_type(2)));
typedef int   i32x4  __attribute__((ext_vector_type(4)));

// exp(x) = 2^(x*log2e); sigmoid(x) = 1/(1+2^(-x*log2e))
#define NL2E (-1.4426950408889634f)
// exp(-d2/5) = 2^(d2 * -log2e/5)
#define C1E  (-0.2885390081777927f)

__device__ __forceinline__ float fast_exp2(float x) {
#if __has_builtin(__builtin_amdgcn_exp2f)
  return __builtin_amdgcn_exp2f(x);
#else
  return __exp2f(x);
#endif
}
__device__ __forceinline__ float fast_rcp(float x) {
#if __has_builtin(__builtin_amdgcn_rcpf)
  return __builtin_amdgcn_rcpf(x);
#else
  return 1.0f / x;
#endif
}
__device__ __forceinline__ float fast_rsq(float x) {
#if __has_builtin(__builtin_amdgcn_rsqf)
  return __builtin_amdgcn_rsqf(x);
#else
  return rsqrtf(x);
#endif
}
__device__ __forceinline__ f32x2 pk_fma(f32x2 a, f32x2 b, f32x2 c) {
  return __builtin_elementwise_fma(a, b, c);
}

// ---------------------------------------------------------------------------
// Edge phase (EXACT R11 structure — measured 145.7 us):
// per wave, 16 n-rows; loop over this block's 64-m range.
// layer1+silu in packed f16 (weights in registers) -> f16 A-frags (no pack)
// -> mfma_16x16x32_f16 -> sigmoid f32 -> num/den f32 regs -> atomicAdd.
// Grid: (NTOT/64) * MSPLIT = 1024 blocks of 256.
// ---------------------------------------------------------------------------
__global__ __launch_bounds__(256, 2)
void edge_kernel(const float* __restrict__ h_l,
                 const float* __restrict__ x_l,
                 const float* __restrict__ h_r,
                 const float* __restrict__ x_r,
                 const float* __restrict__ W1,
                 const float* __restrict__ b1,
                 const float* __restrict__ W2,
                 const float* __restrict__ b2,
                 float* __restrict__ num_g,
                 float* __restrict__ den_g) {
  // hrT[ms][l15*4 + c] = h_r[m][c*16 + l15]  (per-lane float4 -> ds_read_b128)
  __shared__ float hrT[MCHUNK][64];   // 16 KB
  __shared__ float xr_s[MCHUNK][8];   // x_r(3), r_p(3), pad (2 KB)

  const int tid  = threadIdx.x;
  const int wave = tid >> 6;
  const int lane = tid & 63;
  const int l15  = lane & 15;
  const int quad = lane >> 4;

  const int nblk   = blockIdx.x / MSPLIT;
  const int msplit = blockIdx.x % MSPLIT;
  const int n0     = nblk * 64 + wave * 16;
  const int mBase  = msplit * MCHUNK;

  // per-lane A-row n
  const int nA = n0 + l15;
  const float xl0 = x_l[nA * 3 + 0];
  const float xl1 = x_l[nA * 3 + 1];
  const float xl2 = x_l[nA * 3 + 2];
  const float lp0 = h_l[nA * 64 + 61];
  const float lp1 = h_l[nA * 64 + 62];
  const float lp2 = h_l[nA * 64 + 63];

  // layer-1 weights as packed f16 pairs over j (this lane's 16 h1 cols:
  // h1 = quad*8 + j for j<8, 32 + quad*8 + (j-8) for j>=8)
  __half2 w1d2[8], w1h2[8], w1y2[8], b1p2[8];
#pragma unroll
  for (int p = 0; p < 8; ++p) {
    const int j0 = 2 * p, j1 = 2 * p + 1;
    const int hA = (j0 < 8) ? (quad * 8 + j0) : (32 + quad * 8 + (j0 - 8));
    const int hB = (j1 < 8) ? (quad * 8 + j1) : (32 + quad * 8 + (j1 - 8));
    w1d2[p] = __floats2half2_rn(W1[0 * 64 + hA], W1[0 * 64 + hB]);
    w1h2[p] = __floats2half2_rn(W1[1 * 64 + hA], W1[1 * 64 + hB]);
    w1y2[p] = __floats2half2_rn(W1[2 * 64 + hA], W1[2 * 64 + hB]);
    // edge_raw[3] == 1 -> fold W1 row 3 into bias
    b1p2[p] = __floats2half2_rn(b1[hA] + W1[3 * 64 + hA],
                                b1[hB] + W1[3 * 64 + hB]);
  }

  // W2 B-frags (f16): B[k = half*32 + quad*8 + j][col = c*16 + l15]
  f16x8 Bfrag[4][2];
#pragma unroll
  for (int c = 0; c < 4; ++c) {
#pragma unroll
    for (int h = 0; h < 2; ++h) {
      f16x8 f;
#pragma unroll
      for (int j = 0; j < 8; ++j) {
        const int k = h * 32 + quad * 8 + j;
        f[j] = (_Float16)W2[k * 64 + c * 16 + l15];
      }
      Bfrag[c][h] = f;
    }
  }

  // b2 folded into sigmoid exp-arg: arg = e*NL2E + NL2E*b2[h2]
  f32x2 b2c2[4];
#pragma unroll
  for (int c = 0; c < 4; ++c) {
    const float v = NL2E * b2[c * 16 + l15];
    b2c2[c] = f32x2{v, v};
  }

  // stage h_r chunk (transposed groups of 4) + x_r/r_p chunk
  for (int idx = tid; idx < MCHUNK * 64; idx += 256) {
    const int mm = idx >> 6, w = idx & 63;
    const int i = w >> 2, c = w & 3;
    hrT[mm][w] = h_r[(mBase + mm) * 64 + c * 16 + i];
  }
  for (int idx = tid; idx < MCHUNK * 8; idx += 256) {
    const int mm = idx >> 3, k = idx & 7;
    float v = 0.f;
    const int m = mBase + mm;
    if (k < 3)      v = x_r[m * 3 + k];
    else if (k < 6) v = h_r[m * 64 + 61 + (k - 3)];
    xr_s[mm][k] = v;
  }

  const f32x4 zero4 = {0.f, 0.f, 0.f, 0.f};
  const f32x2 one2 = {1.f, 1.f};
  const f32x2 nl2e2 = {NL2E, NL2E};
  const __half2 nl2eh = __float2half2_rn(NL2E);
  const __half2 oneh  = __float2half2_rn(1.0f);
  f32x2 numr2[4][2], denr2[4][2];
#pragma unroll
  for (int c = 0; c < 4; ++c)
#pragma unroll
    for (int h = 0; h < 2; ++h) {
      numr2[c][h] = f32x2{0.f, 0.f};
      denr2[c][h] = f32x2{0.f, 0.f};
    }

  __syncthreads();

#pragma unroll 2
  for (int ms = 0; ms < MCHUNK; ++ms) {
    // broadcast per-m values (same-address LDS reads, vectorized)
    const f32x4 xa = *(const f32x4*)&xr_s[ms][0];   // xr0 xr1 xr2 rp0
    const f32x2 xb = *(const f32x2*)&xr_s[ms][4];   // rp1 rp2
    const float dx = xl0 - xa[0], dy = xl1 - xa[1], dz = xl2 - xa[2];
    const float d2 = fmaf(dz, dz, fmaf(dy, dy, dx * dx));
    const float dist = fast_exp2(d2 * C1E);          // exp(-d2/5)
    const float hb = fmaf(lp1, xa[3], lp0 * xb[0]);
    const float hy = lp2 * xb[1];
    const __half2 dist2 = __float2half2_rn(dist);
    const __half2 hb2 = __float2half2_rn(hb);
    const __half2 hy2 = __float2half2_rn(hy);

    // layer 1 + silu, packed f16, A-frag element order.
    // f16 overflow in e2 (t < ~-11.5) -> inf -> rcp 0 -> s=0 == silu tail. OK.
    __half2 s2[8];
#pragma unroll
    for (int p = 0; p < 8; ++p) {
      const __half2 t2 = __hfma2(dist2, w1d2[p],
                         __hfma2(hb2, w1h2[p],
                         __hfma2(hy2, w1y2[p], b1p2[p])));
      const __half2 a2 = __hmul2(t2, nl2eh);
      const __half2 e2 = h2exp2(a2);
      const __half2 dden = __hadd2(e2, oneh);
      const __half2 r2 = h2rcp(dden);
      s2[p] = __hmul2(t2, r2);                 // silu = t/(1+2^(t*NL2E))
    }
    i32x4 p0, p1;
    p0.x = __builtin_bit_cast(int, s2[0]);  p0.y = __builtin_bit_cast(int, s2[1]);
    p0.z = __builtin_bit_cast(int, s2[2]);  p0.w = __builtin_bit_cast(int, s2[3]);
    p1.x = __builtin_bit_cast(int, s2[4]);  p1.y = __builtin_bit_cast(int, s2[5]);
    p1.z = __builtin_bit_cast(int, s2[6]);  p1.w = __builtin_bit_cast(int, s2[7]);
    const f16x8 A0 = __builtin_bit_cast(f16x8, p0);
    const f16x8 A1 = __builtin_bit_cast(f16x8, p1);

    f32x4 acc[4];
#pragma unroll
    for (int c = 0; c < 4; ++c) {
      acc[c] = __builtin_amdgcn_mfma_f32_16x16x32_f16(A0, Bfrag[c][0], zero4, 0, 0, 0);
      acc[c] = __builtin_amdgcn_mfma_f32_16x16x32_f16(A1, Bfrag[c][1], acc[c], 0, 0, 0);
    }

    // sigmoid + accumulate (f32, r-pairs packed).
    // lane holds e[n = n0+quad*4+r][h2 = c*16+l15]; hrv per c via one b128.
    const f32x4 hrv4 = *(const f32x4*)&hrT[ms][l15 * 4];
#pragma unroll
    for (int c = 0; c < 4; ++c) {
      const f32x2 hrv2 = {hrv4[c], hrv4[c]};
#pragma unroll
      for (int h = 0; h < 2; ++h) {
        const f32x2 a2 = {acc[c][2 * h], acc[c][2 * h + 1]};
        const f32x2 arg = pk_fma(a2, nl2e2, b2c2[c]);
        f32x2 e2;
        e2.x = fast_exp2(arg.x);
        e2.y = fast_exp2(arg.y);
        const f32x2 dden = e2 + one2;
        f32x2 w2;
        w2.x = fast_rcp(dden.x);
        w2.y = fast_rcp(dden.y);
        numr2[c][h] = pk_fma(w2, hrv2, numr2[c][h]);
        denr2[c][h] = denr2[c][h] + w2;
      }
    }
  }

#pragma unroll
  for (int c = 0; c < 4; ++c)
#pragma unroll
    for (int h = 0; h < 2; ++h)
#pragma unroll
      for (int k = 0; k < 2; ++k) {
        const int r = 2 * h + k;
        const int n = n0 + quad * 4 + r;
        const int h2 = c * 16 + l15;
        atomicAdd(&num_g[n * 64 + h2], k ? numr2[c][h].y : numr2[c][h].x);
        atomicAdd(&den_g[n * 64 + h2], k ? denr2[c][h].y : denr2[c][h].x);
      }
}

// ---------------------------------------------------------------------------
// Node phase: NODE_ROWS rows per block (NODE_ROWS/4 per wave, wave-local
// loop, no inner barriers). h_agg = num/(den+1e-6);
// z = cat(h_l,h_agg)@Wn1 + bn1 -> LN -> silu -> @Wn2 + bn2; out = h_l + z.
// Grid: NTOT/NODE_ROWS blocks of 256.
// ---------------------------------------------------------------------------
__global__ __launch_bounds__(256)
void node_kernel(const float* __restrict__ h_l,
                 const float* __restrict__ num_g,
                 const float* __restrict__ den_g,
                 const float* __restrict__ Wn1,
                 const float* __restrict__ bn1,
                 const float* __restrict__ ln_g,
                 const float* __restrict__ ln_b,
                 const float* __restrict__ Wn2,
                 const float* __restrict__ bn2,
                 float* __restrict__ out) {
  __shared__ float Wn1_s[128 * 64];
  __shared__ float Wn2_s[64 * 64];
  __shared__ float xbuf[4][128];
  __shared__ float zbuf[4][64];

  const int tid = threadIdx.x;
  for (int i = tid; i < 128 * 64; i += 256) Wn1_s[i] = Wn1[i];
  for (int i = tid; i < 64 * 64; i += 256) Wn2_s[i] = Wn2[i];

  const int wave = tid >> 6, lane = tid & 63;

  __syncthreads();

#pragma unroll 1
  for (int it = 0; it < NODE_ROWS / 4; ++it) {
    const int row = blockIdx.x * NODE_ROWS + it * 4 + wave;

    const float hl = h_l[row * 64 + lane];
    const float dn = den_g[row * 64 + lane] + 1e-6f;
    const float hagg = num_g[row * 64 + lane] * fast_rcp(dn);
    // xbuf/zbuf are per-wave: no cross-wave barrier needed, LDS ops are
    // wave-ordered (compiler inserts lgkmcnt waits).
    xbuf[wave][lane] = hl;
    xbuf[wave][64 + lane] = hagg;

    float t = bn1[lane];
#pragma unroll 8
    for (int k = 0; k < 128; ++k) t = fmaf(xbuf[wave][k], Wn1_s[k * 64 + lane], t);

    float s1 = t, s2 = t * t;
#pragma unroll
    for (int off = 32; off; off >>= 1) {
      s1 += __shfl_xor(s1, off);
      s2 += __shfl_xor(s2, off);
    }
    const float mu = s1 * 0.015625f;
    const float var = fmaf(s2, 0.015625f, -mu * mu);
    const float rs = fast_rsq(var + 1e-5f);
    const float zn = fmaf((t - mu) * rs, ln_g[lane], ln_b[lane]);
    const float sz = zn * fast_rcp(1.0f + fast_exp2(zn * NL2E));  // silu
    zbuf[wave][lane] = sz;

    float o = bn2[lane];
#pragma unroll 8
    for (int k = 0; k < 64; ++k) o = fmaf(zbuf[wave][k], Wn2_s[k * 64 + lane], o);

    out[row * 64 + lane] = hl + o;
  }
}

extern "C" void kernel_launch(void* const* d_in, const int* in_sizes, int n_in,
                              void* d_out, int out_size, void* d_ws, size_t ws_size,
                              hipStream_t stream) {
  const float* h_l = (const float*)d_in[0];
  const float* x_l = (const float*)d_in[1];
  const float* h_r = (const float*)d_in[2];
  const float* x_r = (const float*)d_in[3];
  const float* W1  = (const float*)d_in[4];
  const float* b1  = (const float*)d_in[5];
  const float* W2  = (const float*)d_in[6];
  const float* b2  = (const float*)d_in[7];
  const float* Wn1 = (const float*)d_in[8];
  const float* bn1 = (const float*)d_in[9];
  const float* lng = (const float*)d_in[10];
  const float* lnb = (const float*)d_in[11];
  const float* Wn2 = (const float*)d_in[12];
  const float* bn2 = (const float*)d_in[13];

  float* num_g = (float*)d_ws;
  float* den_g = num_g + (size_t)NTOT * 64;

  hipMemsetAsync(d_ws, 0, (size_t)NTOT * 64 * 2 * sizeof(float), stream);
  edge_kernel<<<dim3((NTOT / 64) * MSPLIT), dim3(256), 0, stream>>>(
      h_l, x_l, h_r, x_r, W1, b1, W2, b2, num_g, den_g);
  node_kernel<<<dim3(NTOT / NODE_ROWS), dim3(256), 0, stream>>>(
      h_l, num_g, den_g, Wn1, bn1, lng, lnb, Wn2, bn2, (float*)d_out);
}